// Round 6
// baseline (265.048 us; speedup 1.0000x reference)
//
#include <hip/hip_runtime.h>

// ---------------------------------------------------------------------------
// 2-layer GraphSAGE (project=True, aggr='max') on MI355X.
// Round 6: fuse gather-max INTO the dual GEMMs. Per 64-row block:
//   phase 0a: gather-max neighbor rows (half-wave edge pairing, 8-deep
//             unroll, v_pk_max_u16) straight into the LDS A-tile
//   phase 0b: full-K MFMA loop  acc += A_gather @ Wl
//   phase 1 : restage root rows (coalesced) into same LDS, acc += B @ Wr
// Gather (fabric-latency-bound) overlaps MFMA across resident blocks.
// ---------------------------------------------------------------------------

typedef __attribute__((ext_vector_type(8))) short short8;
typedef __attribute__((ext_vector_type(4))) float f32x4;

#define ADJ_CAP 64    // max in-degree slots (Poisson(16): P(deg>=64)*N ~ 5e-15)

__device__ __forceinline__ unsigned short f2bf(float f) {
    unsigned int u = __float_as_uint(f);
    u += 0x7fffu + ((u >> 16) & 1u);          // round-to-nearest-even
    return (unsigned short)(u >> 16);
}

__device__ __forceinline__ unsigned int pkmax(unsigned int a, unsigned int b) {
    unsigned int r;
    asm("v_pk_max_u16 %0, %1, %2" : "=v"(r) : "v"(a), "v"(b));
    return r;
}

// ---- fp32 -> bf16 bulk convert (8 elems/thread) ----
__global__ __launch_bounds__(256) void cvt_bf16_kernel(
    const float* __restrict__ in, unsigned short* __restrict__ out, int n8)
{
    const int i = blockIdx.x * 256 + threadIdx.x;
    if (i >= n8) return;
    const float4 a = *reinterpret_cast<const float4*>(in + (size_t)i * 8);
    const float4 b = *reinterpret_cast<const float4*>(in + (size_t)i * 8 + 4);
    union { unsigned short u[8]; uint4 v; } r;
    r.u[0] = f2bf(a.x); r.u[1] = f2bf(a.y); r.u[2] = f2bf(a.z); r.u[3] = f2bf(a.w);
    r.u[4] = f2bf(b.x); r.u[5] = f2bf(b.y); r.u[6] = f2bf(b.z); r.u[7] = f2bf(b.w);
    *reinterpret_cast<uint4*>(out + (size_t)i * 8) = r.v;
}

// ---- all weights fp32 -> fragment-ready packed bf16 in ONE kernel ----
// pack layout: P[((k>>3)*Nc + c)*8 + (k&7)]
__global__ __launch_bounds__(256) void pack_all_kernel(
    const float* __restrict__ Wp1, const float* __restrict__ Wl1,
    const float* __restrict__ Wr1, const float* __restrict__ Wp2,
    const float* __restrict__ Wl2, const float* __restrict__ Wr2,
    unsigned short* __restrict__ P0, unsigned short* __restrict__ P1,
    unsigned short* __restrict__ P2, unsigned short* __restrict__ P3,
    unsigned short* __restrict__ P4, unsigned short* __restrict__ P5)
{
    const int idx = blockIdx.x * 256 + threadIdx.x;
    const float* W; unsigned short* P; int Nc, local;
    if      (idx <  16384) { W = Wp1; P = P0; Nc = 128; local = idx; }
    else if (idx <  49152) { W = Wl1; P = P1; Nc = 256; local = idx - 16384; }
    else if (idx <  81920) { W = Wr1; P = P2; Nc = 256; local = idx - 49152; }
    else if (idx < 147456) { W = Wp2; P = P3; Nc = 256; local = idx - 81920; }
    else if (idx < 180224) { W = Wl2; P = P4; Nc = 128; local = idx - 147456; }
    else if (idx < 212992) { W = Wr2; P = P5; Nc = 128; local = idx - 180224; }
    else return;
    const int k = local / Nc, c = local % Nc;
    P[((size_t)(k >> 3) * Nc + c) * 8 + (k & 7)] = f2bf(W[local]);
}

// ---- padded adjacency build: deg pre-zeroed; one pass, no scan ----
__global__ __launch_bounds__(256) void build_adj_kernel(
    const int* __restrict__ src, const int* __restrict__ dst,
    int* __restrict__ deg, int* __restrict__ padj, int E)
{
    const int e = blockIdx.x * 256 + threadIdx.x;
    if (e < E) {
        const int d = dst[e];
        const int pos = atomicAdd(&deg[d], 1);
        if (pos < ADJ_CAP) padj[(size_t)d * ADJ_CAP + pos] = src[e];
    }
}

// ---- projection GEMM: out = relu( A @ W + bias ), bf16 out ----
// BM = MF*32 rows x 128 cols per block, 4 waves (2x2), MFx4 16x16 frags/wave.
template<int K, int MF>
__global__ __launch_bounds__(256) void gemm_proj(
    const unsigned short* __restrict__ A,
    const unsigned short* __restrict__ W,
    const float* __restrict__ bias,
    unsigned short* __restrict__ outp,
    int M, int N)
{
    constexpr int BM  = MF * 32;
    constexpr int BK  = 32;
    constexpr int LDK = BK + 8;            // 80B row stride: conflict-free reads
    __shared__ unsigned short As[BM * LDK];

    const int tid  = threadIdx.x;
    const int lane = tid & 63;
    const int wave = tid >> 6;
    const int fr   = lane & 15;
    const int g    = lane >> 4;
    const int bm   = blockIdx.x * BM;
    const int bn   = blockIdx.y * 128;
    const int wr   = (wave >> 1) * (MF * 16);
    const int wc   = (wave & 1) * 64;

    const f32x4 zero = {0.f, 0.f, 0.f, 0.f};
    f32x4 acc[MF][4];
#pragma unroll
    for (int m = 0; m < MF; ++m)
#pragma unroll
        for (int n = 0; n < 4; ++n) acc[m][n] = zero;

    for (int kt = 0; kt < K / BK; ++kt) {
        if (kt) __syncthreads();
#pragma unroll
        for (int c = 0; c < MF / 2; ++c) {
            const int t = tid + c * 256;
            const int r = t >> 2, q = t & 3;
            int gm = bm + r; if (gm >= M) gm = M - 1;   // clamp, never stored
            const short8 v = *reinterpret_cast<const short8*>(
                A + (size_t)gm * K + kt * BK + q * 8);
            *reinterpret_cast<short8*>(&As[r * LDK + q * 8]) = v;
        }
        __syncthreads();
        short8 af[MF];
#pragma unroll
        for (int m = 0; m < MF; ++m)
            af[m] = *reinterpret_cast<const short8*>(
                &As[(wr + m * 16 + fr) * LDK + g * 8]);
#pragma unroll
        for (int n = 0; n < 4; ++n) {
            const int col = bn + wc + n * 16 + fr;
            const short8 bf = *reinterpret_cast<const short8*>(
                W + ((size_t)(kt * 4 + g) * N + col) * 8);
#pragma unroll
            for (int m = 0; m < MF; ++m)
                acc[m][n] = __builtin_amdgcn_mfma_f32_16x16x32_bf16(
                    af[m], bf, acc[m][n], 0, 0, 0);
        }
    }

    float bv[4];
#pragma unroll
    for (int n = 0; n < 4; ++n) bv[n] = bias[bn + wc + n * 16 + fr];
#pragma unroll
    for (int m = 0; m < MF; ++m)
#pragma unroll
        for (int j = 0; j < 4; ++j) {
            const int row = bm + wr + m * 16 + g * 4 + j;
            if (row < M) {
#pragma unroll
                for (int n = 0; n < 4; ++n) {
                    const float v = fmaxf(acc[m][n][j] + bv[n], 0.f);
                    outp[(size_t)row * N + bn + wc + n * 16 + fr] = f2bf(v);
                }
            }
        }
}

// ---- fused gather-max + dual GEMM ----
// out = relu( segment_max(P[adj]) @ Wl + bias + Broot @ Wr ), 64 rows/block,
// full N per block (CF col-frags per wave, NN = CF*64), K-tile lives in LDS.
template<int K, int CF, bool OUT_BF16>
__global__ __launch_bounds__(256) void fused_gather_gemm(
    const unsigned short* __restrict__ P,      // gather source [M,K] bf16
    const unsigned short* __restrict__ Broot,  // root features [M,K] bf16
    const int* __restrict__ padj, const int* __restrict__ deg,
    const unsigned short* __restrict__ Wl,     // packed [K/8][NN][8]
    const unsigned short* __restrict__ Wr,     // packed [K/8][NN][8]
    const float* __restrict__ bias,
    void* __restrict__ outp, int M)
{
    constexpr int NN  = CF * 64;
    constexpr int LDK = K + 8;                 // conflict-free frag reads
    __shared__ unsigned short As[64 * LDK];

    const int tid  = threadIdx.x;
    const int lane = tid & 63;
    const int wave = tid >> 6;
    const int fr   = lane & 15;
    const int g    = lane >> 4;
    const int h    = lane >> 5;                // half-wave id
    const int ll   = lane & 31;
    const int bm   = blockIdx.x * 64;
    const int wc   = wave * (CF * 16);

    // ---- phase 0a: gather-max 16 nodes per wave straight into LDS ----
    for (int i = 0; i < 16; ++i) {
        const int r    = wave * 16 + i;
        const int node = bm + r;
        int d = (node < M) ? deg[node] : 0;
        if (d > ADJ_CAP) d = ADJ_CAP;
        const int* __restrict__ a = padj + (size_t)node * ADJ_CAP;

        if (K == 256) {
            uint4 acm = make_uint4(0u, 0u, 0u, 0u);
            int e = 0;
            for (; e + 8 <= d; e += 8) {
                const int4 sA = *reinterpret_cast<const int4*>(a + e);
                const int4 sB = *reinterpret_cast<const int4*>(a + e + 4);
                const int r0 = h ? sA.y : sA.x, r1 = h ? sA.w : sA.z;
                const int r2 = h ? sB.y : sB.x, r3 = h ? sB.w : sB.z;
                const uint4 v0 = *reinterpret_cast<const uint4*>(P + (size_t)r0 * 256 + ll * 8);
                const uint4 v1 = *reinterpret_cast<const uint4*>(P + (size_t)r1 * 256 + ll * 8);
                const uint4 v2 = *reinterpret_cast<const uint4*>(P + (size_t)r2 * 256 + ll * 8);
                const uint4 v3 = *reinterpret_cast<const uint4*>(P + (size_t)r3 * 256 + ll * 8);
                acm.x = pkmax(acm.x, pkmax(pkmax(v0.x, v1.x), pkmax(v2.x, v3.x)));
                acm.y = pkmax(acm.y, pkmax(pkmax(v0.y, v1.y), pkmax(v2.y, v3.y)));
                acm.z = pkmax(acm.z, pkmax(pkmax(v0.z, v1.z), pkmax(v2.z, v3.z)));
                acm.w = pkmax(acm.w, pkmax(pkmax(v0.w, v1.w), pkmax(v2.w, v3.w)));
            }
            for (; e + 4 <= d; e += 4) {
                const int4 s = *reinterpret_cast<const int4*>(a + e);
                const int r0 = h ? s.y : s.x, r1 = h ? s.w : s.z;
                const uint4 v0 = *reinterpret_cast<const uint4*>(P + (size_t)r0 * 256 + ll * 8);
                const uint4 v1 = *reinterpret_cast<const uint4*>(P + (size_t)r1 * 256 + ll * 8);
                acm.x = pkmax(acm.x, pkmax(v0.x, v1.x));
                acm.y = pkmax(acm.y, pkmax(v0.y, v1.y));
                acm.z = pkmax(acm.z, pkmax(v0.z, v1.z));
                acm.w = pkmax(acm.w, pkmax(v0.w, v1.w));
            }
            for (; e < d; e += 2) {
                const int s0 = a[e];
                const int s1 = (e + 1 < d) ? a[e + 1] : s0;  // dup: max idempotent
                const int rr = h ? s1 : s0;
                const uint4 v = *reinterpret_cast<const uint4*>(P + (size_t)rr * 256 + ll * 8);
                acm.x = pkmax(acm.x, v.x); acm.y = pkmax(acm.y, v.y);
                acm.z = pkmax(acm.z, v.z); acm.w = pkmax(acm.w, v.w);
            }
            acm.x = pkmax(acm.x, (unsigned int)__shfl_xor((int)acm.x, 32, 64));
            acm.y = pkmax(acm.y, (unsigned int)__shfl_xor((int)acm.y, 32, 64));
            acm.z = pkmax(acm.z, (unsigned int)__shfl_xor((int)acm.z, 32, 64));
            acm.w = pkmax(acm.w, (unsigned int)__shfl_xor((int)acm.w, 32, 64));
            if (h == 0)
                *reinterpret_cast<uint4*>(&As[r * LDK + ll * 8]) = acm;
        } else {
            uint2 acm = make_uint2(0u, 0u);
            int e = 0;
            for (; e + 8 <= d; e += 8) {
                const int4 sA = *reinterpret_cast<const int4*>(a + e);
                const int4 sB = *reinterpret_cast<const int4*>(a + e + 4);
                const int r0 = h ? sA.y : sA.x, r1 = h ? sA.w : sA.z;
                const int r2 = h ? sB.y : sB.x, r3 = h ? sB.w : sB.z;
                const uint2 v0 = *reinterpret_cast<const uint2*>(P + (size_t)r0 * 128 + ll * 4);
                const uint2 v1 = *reinterpret_cast<const uint2*>(P + (size_t)r1 * 128 + ll * 4);
                const uint2 v2 = *reinterpret_cast<const uint2*>(P + (size_t)r2 * 128 + ll * 4);
                const uint2 v3 = *reinterpret_cast<const uint2*>(P + (size_t)r3 * 128 + ll * 4);
                acm.x = pkmax(acm.x, pkmax(pkmax(v0.x, v1.x), pkmax(v2.x, v3.x)));
                acm.y = pkmax(acm.y, pkmax(pkmax(v0.y, v1.y), pkmax(v2.y, v3.y)));
            }
            for (; e + 4 <= d; e += 4) {
                const int4 s = *reinterpret_cast<const int4*>(a + e);
                const int r0 = h ? s.y : s.x, r1 = h ? s.w : s.z;
                const uint2 v0 = *reinterpret_cast<const uint2*>(P + (size_t)r0 * 128 + ll * 4);
                const uint2 v1 = *reinterpret_cast<const uint2*>(P + (size_t)r1 * 128 + ll * 4);
                acm.x = pkmax(acm.x, pkmax(v0.x, v1.x));
                acm.y = pkmax(acm.y, pkmax(v0.y, v1.y));
            }
            for (; e < d; e += 2) {
                const int s0 = a[e];
                const int s1 = (e + 1 < d) ? a[e + 1] : s0;
                const int rr = h ? s1 : s0;
                const uint2 v = *reinterpret_cast<const uint2*>(P + (size_t)rr * 128 + ll * 4);
                acm.x = pkmax(acm.x, v.x); acm.y = pkmax(acm.y, v.y);
            }
            acm.x = pkmax(acm.x, (unsigned int)__shfl_xor((int)acm.x, 32, 64));
            acm.y = pkmax(acm.y, (unsigned int)__shfl_xor((int)acm.y, 32, 64));
            if (h == 0)
                *reinterpret_cast<uint2*>(&As[r * LDK + ll * 4]) = acm;
        }
    }

    // acc init AFTER gather keeps gather-phase VGPR low
    const f32x4 zero = {0.f, 0.f, 0.f, 0.f};
    f32x4 acc[4][CF];
#pragma unroll
    for (int m = 0; m < 4; ++m)
#pragma unroll
        for (int n = 0; n < CF; ++n) acc[m][n] = zero;

#pragma unroll
    for (int ph = 0; ph < 2; ++ph) {
        if (ph) {
            __syncthreads();                   // all waves done reading A-tile
            constexpr int CH = K / 8;          // 16B chunks per row
#pragma unroll
            for (int c = 0; c < (64 * CH) / 256; ++c) {
                const int t = tid + c * 256;
                const int r = t / CH, q = t % CH;
                int gm = bm + r; if (gm >= M) gm = M - 1;
                *reinterpret_cast<short8*>(&As[r * LDK + q * 8]) =
                    *reinterpret_cast<const short8*>(Broot + (size_t)gm * K + q * 8);
            }
        }
        __syncthreads();
        const unsigned short* __restrict__ W = ph ? Wr : Wl;
        for (int kt = 0; kt < K / 32; ++kt) {
            short8 af[4];
#pragma unroll
            for (int m = 0; m < 4; ++m)
                af[m] = *reinterpret_cast<const short8*>(
                    &As[(m * 16 + fr) * LDK + kt * 32 + g * 8]);
#pragma unroll
            for (int n = 0; n < CF; ++n) {
                const short8 bf = *reinterpret_cast<const short8*>(
                    W + ((size_t)(kt * 4 + g) * NN + wc + n * 16 + fr) * 8);
#pragma unroll
                for (int m = 0; m < 4; ++m)
                    acc[m][n] = __builtin_amdgcn_mfma_f32_16x16x32_bf16(
                        af[m], bf, acc[m][n], 0, 0, 0);
            }
        }
    }

    // epilogue: + bias, relu, store (D: col=lane&15, row=(lane>>4)*4+j)
    float bv[CF];
#pragma unroll
    for (int n = 0; n < CF; ++n) bv[n] = bias[wc + n * 16 + fr];
#pragma unroll
    for (int m = 0; m < 4; ++m)
#pragma unroll
        for (int j = 0; j < 4; ++j) {
            const int row = bm + m * 16 + g * 4 + j;
            if (row < M) {
#pragma unroll
                for (int n = 0; n < CF; ++n) {
                    const float v = fmaxf(acc[m][n][j] + bv[n], 0.f);
                    const size_t o = (size_t)row * NN + wc + n * 16 + fr;
                    if (OUT_BF16) ((unsigned short*)outp)[o] = f2bf(v);
                    else          ((float*)outp)[o]          = v;
                }
            }
        }
}

extern "C" void kernel_launch(void* const* d_in, const int* in_sizes, int n_in,
                              void* d_out, int out_size, void* d_ws, size_t ws_size,
                              hipStream_t stream)
{
    const float* x   = (const float*)d_in[0];
    const int*   ei  = (const int*)d_in[1];
    const float* Wp1 = (const float*)d_in[2];
    const float* bp1 = (const float*)d_in[3];
    const float* Wl1 = (const float*)d_in[4];
    const float* bl1 = (const float*)d_in[5];
    const float* Wr1 = (const float*)d_in[6];
    const float* Wp2 = (const float*)d_in[7];
    const float* bp2 = (const float*)d_in[8];
    const float* Wl2 = (const float*)d_in[9];
    const float* bl2 = (const float*)d_in[10];
    const float* Wr2 = (const float*)d_in[11];
    float* out = (float*)d_out;

    const int M = in_sizes[0] / 128;      // 50000 nodes
    const int E = in_sizes[1] / 2;        // 800000 edges
    const int* src = ei;
    const int* dst = ei + E;

    // workspace layout (ushort elements first):
    unsigned short* ws  = (unsigned short*)d_ws;
    unsigned short* xb  = ws;                          // M*128
    unsigned short* p1b = xb  + (size_t)M * 128;       // M*128
    unsigned short* h1b = p1b + (size_t)M * 128;       // M*256
    unsigned short* p2b = h1b + (size_t)M * 256;       // M*256
    unsigned short* wpk = p2b + (size_t)M * 256;
    unsigned short* Wp1p = wpk;                        // 128*128
    unsigned short* Wl1p = Wp1p + 128 * 128;           // 128*256
    unsigned short* Wr1p = Wl1p + 128 * 256;           // 128*256
    unsigned short* Wp2p = Wr1p + 128 * 256;           // 256*256
    unsigned short* Wl2p = Wp2p + 256 * 256;           // 256*128
    unsigned short* Wr2p = Wl2p + 256 * 128;           // 256*128
    // int-aligned tail: padded adjacency + degree
    unsigned short* endu = Wr2p + 256 * 128;
    size_t int_off = ((size_t)(endu - ws) * 2 + 15) & ~(size_t)15;   // 16B align
    int* padj = (int*)((char*)d_ws + int_off);         // M*ADJ_CAP ints (12.8MB)
    int* deg  = padj + (size_t)M * ADJ_CAP;            // M ints

    const dim3 blk(256);
    const int eb = (E + 255) / 256;
    const int mb64  = (M + 63) / 64;
    const int mb128 = (M + 127) / 128;

    // ---- prep: convert x, pack weights, build padded adjacency ----
    cvt_bf16_kernel<<<(M * 16 + 255) / 256, blk, 0, stream>>>(x, xb, M * 16);
    pack_all_kernel<<<(212992 + 255) / 256, blk, 0, stream>>>(
        Wp1, Wl1, Wr1, Wp2, Wl2, Wr2, Wp1p, Wl1p, Wr1p, Wp2p, Wl2p, Wr2p);
    hipMemsetAsync(deg, 0, (size_t)M * sizeof(int), stream);
    build_adj_kernel<<<eb, blk, 0, stream>>>(src, dst, deg, padj, E);

    // ---- layer 1 ----
    gemm_proj<128, 2><<<dim3(mb64, 1), blk, 0, stream>>>(
        xb, Wp1p, bp1, p1b, M, 128);
    fused_gather_gemm<128, 4, true><<<mb64, blk, 0, stream>>>(
        p1b, xb, padj, deg, Wl1p, Wr1p, bl1, h1b, M);

    // ---- layer 2 ----
    gemm_proj<256, 4><<<dim3(mb128, 2), blk, 0, stream>>>(
        h1b, Wp2p, bp2, p2b, M, 256);
    fused_gather_gemm<256, 2, false><<<mb64, blk, 0, stream>>>(
        p2b, h1b, padj, deg, Wl2p, Wr2p, bl2, out, M);
}

// Round 7
// 199.969 us; speedup vs baseline: 1.3254x; 1.3254x over previous
//
#include <hip/hip_runtime.h>

// ---------------------------------------------------------------------------
// 2-layer GraphSAGE (project=True, aggr='max') on MI355X.
// Round 7: separate (high-TLP) gathers with 16-edge-wide iterations;
// fused layer tails: tail1 = a1@Wl1 + x@Wr1 -> h1, then h1@Wp2 -> p2 in-LDS;
// tail2 = a2@Wl2 + h1@Wr2 -> out (fp32). cvt kernel dropped.
// ---------------------------------------------------------------------------

typedef __attribute__((ext_vector_type(8))) short short8;
typedef __attribute__((ext_vector_type(4))) float f32x4;

#define ADJ_CAP 64    // max in-degree slots (Poisson(16): P(deg>=64)*N ~ 5e-15)

__device__ __forceinline__ unsigned short f2bf(float f) {
    unsigned int u = __float_as_uint(f);
    u += 0x7fffu + ((u >> 16) & 1u);          // round-to-nearest-even
    return (unsigned short)(u >> 16);
}

__device__ __forceinline__ unsigned int pkmax(unsigned int a, unsigned int b) {
    unsigned int r;
    asm("v_pk_max_u16 %0, %1, %2" : "=v"(r) : "v"(a), "v"(b));
    return r;
}

__device__ __forceinline__ short8 pack8(const float4 f0, const float4 f1) {
    union { unsigned short u[8]; short8 v; } r;
    r.u[0] = f2bf(f0.x); r.u[1] = f2bf(f0.y); r.u[2] = f2bf(f0.z); r.u[3] = f2bf(f0.w);
    r.u[4] = f2bf(f1.x); r.u[5] = f2bf(f1.y); r.u[6] = f2bf(f1.z); r.u[7] = f2bf(f1.w);
    return r.v;
}

// ---- all weights fp32 -> fragment-ready packed bf16 in ONE kernel ----
// pack layout: P[((k>>3)*Nc + c)*8 + (k&7)]
__global__ __launch_bounds__(256) void pack_all_kernel(
    const float* __restrict__ Wp1, const float* __restrict__ Wl1,
    const float* __restrict__ Wr1, const float* __restrict__ Wp2,
    const float* __restrict__ Wl2, const float* __restrict__ Wr2,
    unsigned short* __restrict__ P0, unsigned short* __restrict__ P1,
    unsigned short* __restrict__ P2, unsigned short* __restrict__ P3,
    unsigned short* __restrict__ P4, unsigned short* __restrict__ P5)
{
    const int idx = blockIdx.x * 256 + threadIdx.x;
    const float* W; unsigned short* P; int Nc, local;
    if      (idx <  16384) { W = Wp1; P = P0; Nc = 128; local = idx; }
    else if (idx <  49152) { W = Wl1; P = P1; Nc = 256; local = idx - 16384; }
    else if (idx <  81920) { W = Wr1; P = P2; Nc = 256; local = idx - 49152; }
    else if (idx < 147456) { W = Wp2; P = P3; Nc = 256; local = idx - 81920; }
    else if (idx < 180224) { W = Wl2; P = P4; Nc = 128; local = idx - 147456; }
    else if (idx < 212992) { W = Wr2; P = P5; Nc = 128; local = idx - 180224; }
    else return;
    const int k = local / Nc, c = local % Nc;
    P[((size_t)(k >> 3) * Nc + c) * 8 + (k & 7)] = f2bf(W[local]);
}

// ---- padded adjacency build: deg pre-zeroed; one pass, no scan ----
__global__ __launch_bounds__(256) void build_adj_kernel(
    const int* __restrict__ src, const int* __restrict__ dst,
    int* __restrict__ deg, int* __restrict__ padj, int E)
{
    const int e = blockIdx.x * 256 + threadIdx.x;
    if (e < E) {
        const int d = dst[e];
        const int pos = atomicAdd(&deg[d], 1);
        if (pos < ADJ_CAP) padj[(size_t)d * ADJ_CAP + pos] = src[e];
    }
}

// ---- proj1: p1 = relu( x_f32 @ W + bias ), bf16 out.  K=128, N=128 ----
// 64 rows x 128 cols per block, 4 waves (2x2), 2x4 16x16 frags/wave.
__global__ __launch_bounds__(256) void gemm_proj_f32(
    const float* __restrict__ A,
    const unsigned short* __restrict__ W,
    const float* __restrict__ bias,
    unsigned short* __restrict__ outp,
    int M)
{
    constexpr int K = 128, N = 128, BK = 32, LDK = BK + 8;
    __shared__ unsigned short As[64 * LDK];

    const int tid  = threadIdx.x;
    const int lane = tid & 63;
    const int wave = tid >> 6;
    const int fr   = lane & 15;
    const int g    = lane >> 4;
    const int bm   = blockIdx.x * 64;
    const int wr   = (wave >> 1) * 32;
    const int wc   = (wave & 1) * 64;

    const f32x4 zero = {0.f, 0.f, 0.f, 0.f};
    f32x4 acc[2][4];
#pragma unroll
    for (int m = 0; m < 2; ++m)
#pragma unroll
        for (int n = 0; n < 4; ++n) acc[m][n] = zero;

    for (int kt = 0; kt < K / BK; ++kt) {
        if (kt) __syncthreads();
        {
            const int r = tid >> 2, q = tid & 3;
            const int gm = min(bm + r, M - 1);
            const float4 f0 = *reinterpret_cast<const float4*>(A + (size_t)gm * K + kt * BK + q * 8);
            const float4 f1 = *reinterpret_cast<const float4*>(A + (size_t)gm * K + kt * BK + q * 8 + 4);
            *reinterpret_cast<short8*>(&As[r * LDK + q * 8]) = pack8(f0, f1);
        }
        __syncthreads();
        short8 af[2];
#pragma unroll
        for (int m = 0; m < 2; ++m)
            af[m] = *reinterpret_cast<const short8*>(&As[(wr + m * 16 + fr) * LDK + g * 8]);
#pragma unroll
        for (int n = 0; n < 4; ++n) {
            const short8 bf = *reinterpret_cast<const short8*>(
                W + ((size_t)(kt * 4 + g) * N + wc + n * 16 + fr) * 8);
#pragma unroll
            for (int m = 0; m < 2; ++m)
                acc[m][n] = __builtin_amdgcn_mfma_f32_16x16x32_bf16(af[m], bf, acc[m][n], 0, 0, 0);
        }
    }

    float bv[4];
#pragma unroll
    for (int n = 0; n < 4; ++n) bv[n] = bias[wc + n * 16 + fr];
#pragma unroll
    for (int m = 0; m < 2; ++m)
#pragma unroll
        for (int j = 0; j < 4; ++j) {
            const int row = bm + wr + m * 16 + g * 4 + j;
            if (row < M)
#pragma unroll
                for (int n = 0; n < 4; ++n)
                    outp[(size_t)row * N + wc + n * 16 + fr] =
                        f2bf(fmaxf(acc[m][n][j] + bv[n], 0.f));
        }
}

// ---- gather-max: one wave per node, 16 edges per iteration ----
// D=128: quarter-wave per edge (16 lanes x 16B = full row), 4 loads/lane.
// D=256: half-wave per edge (32 lanes x 16B = full row), 8 loads/lane.
// Tail: idx clamped to d-1 (duplicate rows; max idempotent, same-addr L1 hit).
template<int D>
__global__ __launch_bounds__(256) void gather_max_bf16(
    const unsigned short* __restrict__ p, const int* __restrict__ padj,
    const int* __restrict__ deg, unsigned short* __restrict__ aggr, int n)
{
    const int node = (blockIdx.x * 256 + threadIdx.x) >> 6;
    const int lane = threadIdx.x & 63;
    if (node >= n) return;
    int d = deg[node];
    if (d > ADJ_CAP) d = ADJ_CAP;
    const int* __restrict__ a = padj + (size_t)node * ADJ_CAP;

    if (D == 128) {
        const int q  = lane >> 4;          // quarter id: edge slot
        const int ll = lane & 15;          // 16 lanes x uint4 = 256B row
        uint4 acc = make_uint4(0u, 0u, 0u, 0u);
        for (int e = 0; e < d; e += 16) {
            const int i0 = min(e + q,      d - 1);
            const int i1 = min(e + 4 + q,  d - 1);
            const int i2 = min(e + 8 + q,  d - 1);
            const int i3 = min(e + 12 + q, d - 1);
            const int r0 = a[i0], r1 = a[i1], r2 = a[i2], r3 = a[i3];
            const uint4 v0 = *reinterpret_cast<const uint4*>(p + (size_t)r0 * 128 + ll * 8);
            const uint4 v1 = *reinterpret_cast<const uint4*>(p + (size_t)r1 * 128 + ll * 8);
            const uint4 v2 = *reinterpret_cast<const uint4*>(p + (size_t)r2 * 128 + ll * 8);
            const uint4 v3 = *reinterpret_cast<const uint4*>(p + (size_t)r3 * 128 + ll * 8);
            acc.x = pkmax(acc.x, pkmax(pkmax(v0.x, v1.x), pkmax(v2.x, v3.x)));
            acc.y = pkmax(acc.y, pkmax(pkmax(v0.y, v1.y), pkmax(v2.y, v3.y)));
            acc.z = pkmax(acc.z, pkmax(pkmax(v0.z, v1.z), pkmax(v2.z, v3.z)));
            acc.w = pkmax(acc.w, pkmax(pkmax(v0.w, v1.w), pkmax(v2.w, v3.w)));
        }
        acc.x = pkmax(acc.x, (unsigned int)__shfl_xor((int)acc.x, 16, 64));
        acc.y = pkmax(acc.y, (unsigned int)__shfl_xor((int)acc.y, 16, 64));
        acc.z = pkmax(acc.z, (unsigned int)__shfl_xor((int)acc.z, 16, 64));
        acc.w = pkmax(acc.w, (unsigned int)__shfl_xor((int)acc.w, 16, 64));
        acc.x = pkmax(acc.x, (unsigned int)__shfl_xor((int)acc.x, 32, 64));
        acc.y = pkmax(acc.y, (unsigned int)__shfl_xor((int)acc.y, 32, 64));
        acc.z = pkmax(acc.z, (unsigned int)__shfl_xor((int)acc.z, 32, 64));
        acc.w = pkmax(acc.w, (unsigned int)__shfl_xor((int)acc.w, 32, 64));
        if (lane < 16)
            *reinterpret_cast<uint4*>(aggr + (size_t)node * 128 + ll * 8) = acc;
    } else {
        const int h  = lane >> 5;          // half id: edge slot
        const int ll = lane & 31;          // 32 lanes x uint4 = 512B row
        uint4 acc = make_uint4(0u, 0u, 0u, 0u);
        for (int e = 0; e < d; e += 16) {
            const int i0 = min(e + h,      d - 1);
            const int i1 = min(e + 2 + h,  d - 1);
            const int i2 = min(e + 4 + h,  d - 1);
            const int i3 = min(e + 6 + h,  d - 1);
            const int i4 = min(e + 8 + h,  d - 1);
            const int i5 = min(e + 10 + h, d - 1);
            const int i6 = min(e + 12 + h, d - 1);
            const int i7 = min(e + 14 + h, d - 1);
            const int r0 = a[i0], r1 = a[i1], r2 = a[i2], r3 = a[i3];
            const int r4 = a[i4], r5 = a[i5], r6 = a[i6], r7 = a[i7];
            const uint4 v0 = *reinterpret_cast<const uint4*>(p + (size_t)r0 * 256 + ll * 8);
            const uint4 v1 = *reinterpret_cast<const uint4*>(p + (size_t)r1 * 256 + ll * 8);
            const uint4 v2 = *reinterpret_cast<const uint4*>(p + (size_t)r2 * 256 + ll * 8);
            const uint4 v3 = *reinterpret_cast<const uint4*>(p + (size_t)r3 * 256 + ll * 8);
            const uint4 v4 = *reinterpret_cast<const uint4*>(p + (size_t)r4 * 256 + ll * 8);
            const uint4 v5 = *reinterpret_cast<const uint4*>(p + (size_t)r5 * 256 + ll * 8);
            const uint4 v6 = *reinterpret_cast<const uint4*>(p + (size_t)r6 * 256 + ll * 8);
            const uint4 v7 = *reinterpret_cast<const uint4*>(p + (size_t)r7 * 256 + ll * 8);
            acc.x = pkmax(acc.x, pkmax(pkmax(pkmax(v0.x, v1.x), pkmax(v2.x, v3.x)),
                                        pkmax(pkmax(v4.x, v5.x), pkmax(v6.x, v7.x))));
            acc.y = pkmax(acc.y, pkmax(pkmax(pkmax(v0.y, v1.y), pkmax(v2.y, v3.y)),
                                        pkmax(pkmax(v4.y, v5.y), pkmax(v6.y, v7.y))));
            acc.z = pkmax(acc.z, pkmax(pkmax(pkmax(v0.z, v1.z), pkmax(v2.z, v3.z)),
                                        pkmax(pkmax(v4.z, v5.z), pkmax(v6.z, v7.z))));
            acc.w = pkmax(acc.w, pkmax(pkmax(pkmax(v0.w, v1.w), pkmax(v2.w, v3.w)),
                                        pkmax(pkmax(v4.w, v5.w), pkmax(v6.w, v7.w))));
        }
        acc.x = pkmax(acc.x, (unsigned int)__shfl_xor((int)acc.x, 32, 64));
        acc.y = pkmax(acc.y, (unsigned int)__shfl_xor((int)acc.y, 32, 64));
        acc.z = pkmax(acc.z, (unsigned int)__shfl_xor((int)acc.z, 32, 64));
        acc.w = pkmax(acc.w, (unsigned int)__shfl_xor((int)acc.w, 32, 64));
        if (lane < 32)
            *reinterpret_cast<uint4*>(aggr + (size_t)node * 256 + ll * 8) = acc;
    }
}

// ---- tail1: h1 = relu(a1@Wl1 + x@Wr1 + bl1); p2 = relu(h1@Wp2 + bp2) ----
// 64 rows/block, full N=256; 4 waves, each owns 64 cols (4 frags).
__global__ __launch_bounds__(256) void tail1_kernel(
    const unsigned short* __restrict__ a1,   // [M,128] bf16
    const float* __restrict__ x,             // [M,128] fp32
    const unsigned short* __restrict__ Wl,   // packed, Nc=256
    const unsigned short* __restrict__ Wr,   // packed, Nc=256
    const float* __restrict__ bl,
    const unsigned short* __restrict__ Wp2,  // packed, Nc=256 (K=256)
    const float* __restrict__ bp2,
    unsigned short* __restrict__ h1,         // [M,256] bf16
    unsigned short* __restrict__ p2,         // [M,256] bf16
    int M)
{
    constexpr int LDK = 128 + 8;             // a/x tile stride
    constexpr int LDH = 256 + 8;             // h tile stride
    __shared__ unsigned short As[64 * LDK];  // 17.4 KB
    __shared__ unsigned short Hs[64 * LDH];  // 33.8 KB

    const int tid  = threadIdx.x;
    const int lane = tid & 63;
    const int wave = tid >> 6;
    const int fr   = lane & 15;
    const int g    = lane >> 4;
    const int bm   = blockIdx.x * 64;
    const int wc   = wave * 64;

    const f32x4 zero = {0.f, 0.f, 0.f, 0.f};
    f32x4 acc[4][4];
#pragma unroll
    for (int m = 0; m < 4; ++m)
#pragma unroll
        for (int n = 0; n < 4; ++n) acc[m][n] = zero;

    // phase A: stage a1 tile [64x128] and MFMA @ Wl
#pragma unroll
    for (int c = 0; c < 4; ++c) {
        const int t = tid + c * 256;
        const int r = t >> 4, q = t & 15;
        const int gm = min(bm + r, M - 1);
        *reinterpret_cast<short8*>(&As[r * LDK + q * 8]) =
            *reinterpret_cast<const short8*>(a1 + (size_t)gm * 128 + q * 8);
    }
    __syncthreads();
#pragma unroll
    for (int kt = 0; kt < 4; ++kt) {
        short8 af[4];
#pragma unroll
        for (int m = 0; m < 4; ++m)
            af[m] = *reinterpret_cast<const short8*>(&As[(m * 16 + fr) * LDK + kt * 32 + g * 8]);
#pragma unroll
        for (int n = 0; n < 4; ++n) {
            const short8 bf = *reinterpret_cast<const short8*>(
                Wl + ((size_t)(kt * 4 + g) * 256 + wc + n * 16 + fr) * 8);
#pragma unroll
            for (int m = 0; m < 4; ++m)
                acc[m][n] = __builtin_amdgcn_mfma_f32_16x16x32_bf16(af[m], bf, acc[m][n], 0, 0, 0);
        }
    }
    __syncthreads();
    // phase B: stage x (fp32->bf16) and MFMA @ Wr (accumulate)
#pragma unroll
    for (int c = 0; c < 4; ++c) {
        const int t = tid + c * 256;
        const int r = t >> 4, q = t & 15;
        const int gm = min(bm + r, M - 1);
        const float4 f0 = *reinterpret_cast<const float4*>(x + (size_t)gm * 128 + q * 8);
        const float4 f1 = *reinterpret_cast<const float4*>(x + (size_t)gm * 128 + q * 8 + 4);
        *reinterpret_cast<short8*>(&As[r * LDK + q * 8]) = pack8(f0, f1);
    }
    __syncthreads();
#pragma unroll
    for (int kt = 0; kt < 4; ++kt) {
        short8 af[4];
#pragma unroll
        for (int m = 0; m < 4; ++m)
            af[m] = *reinterpret_cast<const short8*>(&As[(m * 16 + fr) * LDK + kt * 32 + g * 8]);
#pragma unroll
        for (int n = 0; n < 4; ++n) {
            const short8 bf = *reinterpret_cast<const short8*>(
                Wr + ((size_t)(kt * 4 + g) * 256 + wc + n * 16 + fr) * 8);
#pragma unroll
            for (int m = 0; m < 4; ++m)
                acc[m][n] = __builtin_amdgcn_mfma_f32_16x16x32_bf16(af[m], bf, acc[m][n], 0, 0, 0);
        }
    }

    // epilogue 1: h = relu(acc + bl) -> global h1 + LDS Hs
    {
        float bv[4];
#pragma unroll
        for (int n = 0; n < 4; ++n) bv[n] = bl[wc + n * 16 + fr];
#pragma unroll
        for (int m = 0; m < 4; ++m)
#pragma unroll
            for (int j = 0; j < 4; ++j) {
                const int rl = m * 16 + g * 4 + j;
#pragma unroll
                for (int n = 0; n < 4; ++n) {
                    const unsigned short hb = f2bf(fmaxf(acc[m][n][j] + bv[n], 0.f));
                    Hs[rl * LDH + wc + n * 16 + fr] = hb;
                    if (bm + rl < M)
                        h1[(size_t)(bm + rl) * 256 + wc + n * 16 + fr] = hb;
                }
            }
    }
    __syncthreads();

    // phase C: p2 = relu(Hs @ Wp2 + bp2), K=256
#pragma unroll
    for (int m = 0; m < 4; ++m)
#pragma unroll
        for (int n = 0; n < 4; ++n) acc[m][n] = zero;
#pragma unroll
    for (int kt = 0; kt < 8; ++kt) {
        short8 af[4];
#pragma unroll
        for (int m = 0; m < 4; ++m)
            af[m] = *reinterpret_cast<const short8*>(&Hs[(m * 16 + fr) * LDH + kt * 32 + g * 8]);
#pragma unroll
        for (int n = 0; n < 4; ++n) {
            const short8 bf = *reinterpret_cast<const short8*>(
                Wp2 + ((size_t)(kt * 4 + g) * 256 + wc + n * 16 + fr) * 8);
#pragma unroll
            for (int m = 0; m < 4; ++m)
                acc[m][n] = __builtin_amdgcn_mfma_f32_16x16x32_bf16(af[m], bf, acc[m][n], 0, 0, 0);
        }
    }
    {
        float bv[4];
#pragma unroll
        for (int n = 0; n < 4; ++n) bv[n] = bp2[wc + n * 16 + fr];
#pragma unroll
        for (int m = 0; m < 4; ++m)
#pragma unroll
            for (int j = 0; j < 4; ++j) {
                const int row = bm + m * 16 + g * 4 + j;
                if (row < M)
#pragma unroll
                    for (int n = 0; n < 4; ++n)
                        p2[(size_t)row * 256 + wc + n * 16 + fr] =
                            f2bf(fmaxf(acc[m][n][j] + bv[n], 0.f));
            }
    }
}

// ---- tail2: out = relu(a2@Wl2 + h1@Wr2 + bl2), fp32 out, N=128, K=256 ----
// 64 rows/block, 4 waves, each owns 32 cols (2 frags). Full-K LDS tile.
__global__ __launch_bounds__(256) void tail2_kernel(
    const unsigned short* __restrict__ a2,   // [M,256] bf16
    const unsigned short* __restrict__ h1,   // [M,256] bf16
    const unsigned short* __restrict__ Wl,   // packed, Nc=128
    const unsigned short* __restrict__ Wr,   // packed, Nc=128
    const float* __restrict__ bl,
    float* __restrict__ out, int M)
{
    constexpr int LDK = 256 + 8;
    __shared__ unsigned short As[64 * LDK];  // 33.8 KB

    const int tid  = threadIdx.x;
    const int lane = tid & 63;
    const int wave = tid >> 6;
    const int fr   = lane & 15;
    const int g    = lane >> 4;
    const int bm   = blockIdx.x * 64;
    const int wc   = wave * 32;

    const f32x4 zero = {0.f, 0.f, 0.f, 0.f};
    f32x4 acc[4][2];
#pragma unroll
    for (int m = 0; m < 4; ++m)
#pragma unroll
        for (int n = 0; n < 2; ++n) acc[m][n] = zero;

#pragma unroll
    for (int ph = 0; ph < 2; ++ph) {
        const unsigned short* __restrict__ P = ph ? h1 : a2;
        const unsigned short* __restrict__ W = ph ? Wr : Wl;
        if (ph) __syncthreads();
#pragma unroll
        for (int c = 0; c < 8; ++c) {
            const int t = tid + c * 256;
            const int r = t >> 5, q = t & 31;
            const int gm = min(bm + r, M - 1);
            *reinterpret_cast<short8*>(&As[r * LDK + q * 8]) =
                *reinterpret_cast<const short8*>(P + (size_t)gm * 256 + q * 8);
        }
        __syncthreads();
#pragma unroll
        for (int kt = 0; kt < 8; ++kt) {
            short8 af[4];
#pragma unroll
            for (int m = 0; m < 4; ++m)
                af[m] = *reinterpret_cast<const short8*>(&As[(m * 16 + fr) * LDK + kt * 32 + g * 8]);
#pragma unroll
            for (int n = 0; n < 2; ++n) {
                const short8 bf = *reinterpret_cast<const short8*>(
                    W + ((size_t)(kt * 4 + g) * 128 + wc + n * 16 + fr) * 8);
#pragma unroll
                for (int m = 0; m < 4; ++m)
                    acc[m][n] = __builtin_amdgcn_mfma_f32_16x16x32_bf16(af[m], bf, acc[m][n], 0, 0, 0);
            }
        }
    }

    float bv[2];
#pragma unroll
    for (int n = 0; n < 2; ++n) bv[n] = bl[wc + n * 16 + fr];
#pragma unroll
    for (int m = 0; m < 4; ++m)
#pragma unroll
        for (int j = 0; j < 4; ++j) {
            const int row = bm + m * 16 + g * 4 + j;
            if (row < M)
#pragma unroll
                for (int n = 0; n < 2; ++n)
                    out[(size_t)row * 128 + wc + n * 16 + fr] =
                        fmaxf(acc[m][n][j] + bv[n], 0.f);
        }
}

extern "C" void kernel_launch(void* const* d_in, const int* in_sizes, int n_in,
                              void* d_out, int out_size, void* d_ws, size_t ws_size,
                              hipStream_t stream)
{
    const float* x   = (const float*)d_in[0];
    const int*   ei  = (const int*)d_in[1];
    const float* Wp1 = (const float*)d_in[2];
    const float* bp1 = (const float*)d_in[3];
    const float* Wl1 = (const float*)d_in[4];
    const float* bl1 = (const float*)d_in[5];
    const float* Wr1 = (const float*)d_in[6];
    const float* Wp2 = (const float*)d_in[7];
    const float* bp2 = (const float*)d_in[8];
    const float* Wl2 = (const float*)d_in[9];
    const float* bl2 = (const float*)d_in[10];
    const float* Wr2 = (const float*)d_in[11];
    float* out = (float*)d_out;

    const int M = in_sizes[0] / 128;      // 50000 nodes
    const int E = in_sizes[1] / 2;        // 800000 edges
    const int* src = ei;
    const int* dst = ei + E;

    // workspace layout (ushort elements first):
    unsigned short* ws  = (unsigned short*)d_ws;
    unsigned short* p1b = ws;                          // M*128
    unsigned short* a1b = p1b + (size_t)M * 128;       // M*128
    unsigned short* h1b = a1b + (size_t)M * 128;       // M*256
    unsigned short* p2b = h1b + (size_t)M * 256;       // M*256
    unsigned short* a2b = p2b + (size_t)M * 256;       // M*256
    unsigned short* wpk = a2b + (size_t)M * 256;
    unsigned short* Wp1p = wpk;                        // 128*128
    unsigned short* Wl1p = Wp1p + 128 * 128;           // 128*256
    unsigned short* Wr1p = Wl1p + 128 * 256;           // 128*256
    unsigned short* Wp2p = Wr1p + 128 * 256;           // 256*256
    unsigned short* Wl2p = Wp2p + 256 * 256;           // 256*128
    unsigned short* Wr2p = Wl2p + 256 * 128;           // 256*128
    unsigned short* endu = Wr2p + 256 * 128;
    size_t int_off = ((size_t)(endu - ws) * 2 + 15) & ~(size_t)15;   // 16B align
    int* padj = (int*)((char*)d_ws + int_off);         // M*ADJ_CAP ints (12.8MB)
    int* deg  = padj + (size_t)M * ADJ_CAP;            // M ints

    const dim3 blk(256);
    const int eb = (E + 255) / 256;
    const int gb = (M + 3) / 4;           // gather: 4 waves (nodes) per block
    const int mb64 = (M + 63) / 64;

    // ---- prep ----
    pack_all_kernel<<<(212992 + 255) / 256, blk, 0, stream>>>(
        Wp1, Wl1, Wr1, Wp2, Wl2, Wr2, Wp1p, Wl1p, Wr1p, Wp2p, Wl2p, Wr2p);
    hipMemsetAsync(deg, 0, (size_t)M * sizeof(int), stream);
    build_adj_kernel<<<eb, blk, 0, stream>>>(src, dst, deg, padj, E);

    // ---- layer 1 ----
    gemm_proj_f32<<<mb64, blk, 0, stream>>>(x, Wp1p, bp1, p1b, M);
    gather_max_bf16<128><<<gb, blk, 0, stream>>>(p1b, padj, deg, a1b, M);
    tail1_kernel<<<mb64, blk, 0, stream>>>(
        a1b, x, Wl1p, Wr1p, bl1, Wp2p, bp2, h1b, p2b, M);

    // ---- layer 2 ----
    gather_max_bf16<256><<<gb, blk, 0, stream>>>(p2b, padj, deg, a2b, M);
    tail2_kernel<<<mb64, blk, 0, stream>>>(
        a2b, h1b, Wl2p, Wr2p, bl2, out, M);
}